// Round 7
// baseline (183.797 us; speedup 1.0000x reference)
//
#include <hip/hip_runtime.h>

#define NROWS 8192
#define DDIM  256
#define KSPLIT 8
#define BM 256
#define BK 64
#define NT (NROWS / KSPLIT / BK)   // 16 tiles per split

typedef __bf16 bf16x8 __attribute__((ext_vector_type(8)));
typedef float  f32x4  __attribute__((ext_vector_type(4)));
typedef float  f32x16 __attribute__((ext_vector_type(16)));

typedef __attribute__((address_space(1))) unsigned int uint_gas;
typedef __attribute__((address_space(3))) unsigned int uint_las;

__device__ __forceinline__ void gload_lds16(const void* g, void* l) {
  __builtin_amdgcn_global_load_lds((const uint_gas*)g, (uint_las*)l, 16, 0, 0);
}

__device__ __forceinline__ unsigned int f2bf_bits(float f) {
  union { float f; unsigned int u; } v; v.f = f;
  unsigned int r = v.u + 0x7FFFu + ((v.u >> 16) & 1u);
  return r >> 16;
}
__device__ __forceinline__ float bf2f(unsigned int b) {
  union { unsigned int u; float f; } v; v.u = b << 16;
  return v.f;
}
// pack two f32 -> one u32 of 2x bf16 (RNE); compiler emits v_cvt_pk_bf16_f32
__device__ __forceinline__ unsigned int pack2bf(float a, float b) {
  union { unsigned int u; __bf16 h[2]; } p;
  p.h[0] = (__bf16)a; p.h[1] = (__bf16)b;
  return p.u;
}
__device__ __forceinline__ unsigned short f2h_bits(float f) {
  union { _Float16 h; unsigned short u; } c; c.h = (_Float16)f;
  return c.u;
}
__device__ __forceinline__ float h2f(unsigned short u) {
  union { unsigned short u; _Float16 h; } c; c.u = u;
  return (float)c.h;
}
__device__ __forceinline__ bf16x8 cvt8(const float* p) {
  float4 f0 = *(const float4*)p;
  float4 f1 = *(const float4*)(p + 4);
  union { bf16x8 v; unsigned short s[8]; } u;
  u.s[0] = (unsigned short)f2bf_bits(f0.x);
  u.s[1] = (unsigned short)f2bf_bits(f0.y);
  u.s[2] = (unsigned short)f2bf_bits(f0.z);
  u.s[3] = (unsigned short)f2bf_bits(f0.w);
  u.s[4] = (unsigned short)f2bf_bits(f1.x);
  u.s[5] = (unsigned short)f2bf_bits(f1.y);
  u.s[6] = (unsigned short)f2bf_bits(f1.z);
  u.s[7] = (unsigned short)f2bf_bits(f1.w);
  return u.v;
}

// ---------------- kernel 1: QKV projections + L2 norm + vT (convert folded in) ----------------
// grid = 384: out = bid/128 (0=q,1=k,2=v), mb = bid%128 (64-row slab)
__global__ __launch_bounds__(256) void qkv_kernel(
    const float* __restrict__ bq, const float* __restrict__ bk, const float* __restrict__ bv,
    const float* __restrict__ x,
    const float* __restrict__ wq, const float* __restrict__ wk, const float* __restrict__ wv,
    unsigned short* __restrict__ qb, unsigned short* __restrict__ kb,
    unsigned short* __restrict__ vb, unsigned short* __restrict__ vT)
{
  __shared__ unsigned short vstage[DDIM * 72];
  const int t = threadIdx.x;
  const int w = t >> 6, l = t & 63;
  const int c = l & 15, g = l >> 4;
  const int out = blockIdx.x / 128;
  const int mb  = blockIdx.x % 128;
  const int row0 = mb * 64;
  const int rw = row0 + w * 16;

  // load x rows as fp32, convert to bf16 fragments in-register
  bf16x8 a[8];
  #pragma unroll
  for (int ks = 0; ks < 8; ks++)
    a[ks] = cvt8(x + (size_t)(rw + c) * DDIM + ks * 32 + g * 8);

  const float* Wf = (out == 0) ? wq : (out == 1) ? wk : wv;
  const float* bias = (out == 0) ? bq : (out == 1) ? bk : bv;
  unsigned short* dst = (out == 0) ? qb : (out == 1) ? kb : vb;
  f32x4 vals[16];
  #pragma unroll
  for (int ct = 0; ct < 16; ct++) {
    f32x4 acc = {0.f, 0.f, 0.f, 0.f};
    #pragma unroll
    for (int ks = 0; ks < 8; ks++) {
      bf16x8 b = cvt8(Wf + (size_t)(ct * 16 + c) * DDIM + ks * 32 + g * 8);
      acc = __builtin_amdgcn_mfma_f32_16x16x32_bf16(a[ks], b, acc, 0, 0, 0);
    }
    float bias_v = bias[ct * 16 + c];
    #pragma unroll
    for (int r = 0; r < 4; r++) acc[r] += bias_v;
    vals[ct] = acc;
  }
  if (out < 2) {   // L2 normalize rows (q, k)
    #pragma unroll
    for (int r = 0; r < 4; r++) {
      float ss = 0.f;
      #pragma unroll
      for (int ct = 0; ct < 16; ct++) ss += vals[ct][r] * vals[ct][r];
      ss += __shfl_xor(ss, 1); ss += __shfl_xor(ss, 2);
      ss += __shfl_xor(ss, 4); ss += __shfl_xor(ss, 8);
      float inv = 1.f / fmaxf(sqrtf(ss), 1e-12f);
      #pragma unroll
      for (int ct = 0; ct < 16; ct++) vals[ct][r] *= inv;
    }
  }
  #pragma unroll
  for (int ct = 0; ct < 16; ct++) {
    #pragma unroll
    for (int r = 0; r < 4; r++) {
      unsigned int bits = f2bf_bits(vals[ct][r]);
      unsigned int ob = (unsigned int)__shfl_xor((int)bits, 1);
      if (!(l & 1))
        *(unsigned int*)(dst + (size_t)(rw + g * 4 + r) * DDIM + ct * 16 + c) =
            bits | (ob << 16);
      if (out == 2)
        vstage[(ct * 16 + c) * 72 + (w * 16 + g * 4 + r)] = (unsigned short)bits;
    }
  }
  if (out == 2) {
    __syncthreads();
    #pragma unroll
    for (int p = 0; p < 8; p++) {
      int dd = (t >> 3) + p * 32;
      int ch = t & 7;
      *(uint4*)(vT + (size_t)dd * NROWS + row0 + ch * 8) =
          *(const uint4*)(vstage + dd * 72 + ch * 8);
    }
  }
}

// ---------------- kernel 2: fused relu-attention partials (BM=256, 32x32x16) ----------------
// 8 waves. S-phase: wave w owns qrows w*32..+32 (qa hoisted, lane&31 = qrow),
// swapped mfma(K,Q) -> S^T, 2 sequential kcol tiles, per-lane den, cvt_pk pack.
// PV-phase: wave w -> (a=w>>1: qrow64, h=w&1: dcol128), 2x4 32x32 tiles,
// pa[2]+vf[4] per chunk = 6 reads / 8 MFMA.
__global__ __launch_bounds__(512, 1) void attn_kernel(
    const unsigned short* __restrict__ qb, const unsigned short* __restrict__ kb,
    const unsigned short* __restrict__ vT,
    unsigned short* __restrict__ nump, float* __restrict__ denp)
{
  // 2x32KB K dbuf | 2x32KB vT dbuf | 32KB P ([256][64] bf16, XOR-swizzled)
  __shared__ __align__(16) char smem[163840];
  char* kbuf = smem;
  char* vbuf = smem + 65536;
  char* P    = smem + 131072;

  const int t = threadIdx.x;
  const int w = t >> 6, l = t & 63;
  const int l31 = l & 31, hi = l >> 5;
  const int a = w >> 1, h = w & 1;     // PV: qrow64 group 0..3, dcol128 half 0..1
  const int bid = blockIdx.x;
  const int split = bid & (KSPLIT - 1);
  const int mb = bid >> 3;
  const int q0 = mb * BM;
  const int kbase0 = split * (NROWS / KSPLIT);

  const char* kbc = (const char*)kb;
  const char* vtc = (const char*)vT;

  // hoist q fragments: lane&31 = qrow (w*32+l31), 16 K-chunks = 64 VGPR
  bf16x8 qa[16];
  {
    const unsigned short* qrowp = qb + (size_t)(q0 + w * 32 + l31) * DDIM + hi * 8;
    #pragma unroll
    for (int m = 0; m < 16; m++)
      qa[m] = *(const bf16x8*)(qrowp + m * 16);
  }

  f32x16 oacc[2][4];
  #pragma unroll
  for (int tt = 0; tt < 2; tt++)
    #pragma unroll
    for (int dt = 0; dt < 4; dt++)
      oacc[tt][dt] = (f32x16){0.f};
  float denl = 0.f;   // per-lane row sum: qrow = w*32+l31, this lane's kcols

  auto stage = [&](int buf, int it) {
    const int kbase = kbase0 + it * BK;
    const char* ksrc = kbc + (size_t)kbase * 512;
    #pragma unroll
    for (int i = 0; i < 4; i++) {
      int n = i * 512 + t;
      int row = n >> 5, slot = n & 31;
      gload_lds16(ksrc + row * 512 + ((slot ^ (row & 7)) * 16),
                  kbuf + buf * 32768 + i * 8192 + w * 1024);
    }
    const char* vsrc = vtc + (size_t)kbase * 2;
    #pragma unroll
    for (int i = 0; i < 4; i++) {
      int n = i * 512 + t;
      int dd = n >> 3, slot = n & 7;
      gload_lds16(vsrc + (size_t)dd * (NROWS * 2) + ((slot ^ (dd & 7)) * 16),
                  vbuf + buf * 32768 + i * 8192 + w * 1024);
    }
  };

  // prologue: stage tile 0 into buf 0
  stage(0, 0);
  asm volatile("s_waitcnt vmcnt(0)" ::: "memory");
  __builtin_amdgcn_sched_barrier(0);
  __builtin_amdgcn_s_barrier();
  __builtin_amdgcn_sched_barrier(0);

  for (int it = 0; it < NT; ++it) {
    const int cur = it & 1;
    if (it + 1 < NT) stage(cur ^ 1, it + 1);
    __builtin_amdgcn_sched_barrier(0);

    // ---- S^T = K.Q^T: wave's 32 qrows x 64 kcols, 2 sequential 32x32 tiles ----
    const char* kcur = kbuf + cur * 32768;
    const int qrow = w * 32 + l31;
    char* prow = P + qrow * 128;
    const int pswz = (qrow & 7) << 4;
    #pragma unroll
    for (int c = 0; c < 2; c++) {
      const int krl = c * 32 + l31;
      const int kswz = (krl & 7) << 4;
      f32x16 sacc = (f32x16){0.f};
      #pragma unroll
      for (int m = 0; m < 16; m++) {
        bf16x8 kf = *(const bf16x8*)(kcur + krl * 512 + ((m * 32 + hi * 16) ^ kswz));
        sacc = __builtin_amdgcn_mfma_f32_32x32x16_bf16(kf, qa[m], sacc, 0, 0, 0);
      }
      // relu + per-lane den + in-lane bf16 pack (lane's qrow, 16 of 32 kcols)
      #pragma unroll
      for (int q = 0; q < 4; q++) {
        float v0 = fmaxf(sacc[4 * q + 0], 0.f);
        float v1 = fmaxf(sacc[4 * q + 1], 0.f);
        float v2 = fmaxf(sacc[4 * q + 2], 0.f);
        float v3 = fmaxf(sacc[4 * q + 3], 0.f);
        denl += (v0 + v1) + (v2 + v3);
        uint2 d2;
        d2.x = pack2bf(v0, v1);
        d2.y = pack2bf(v2, v3);
        // kcol = c*32 + 8q + 4hi + j  -> byte col = c*64 + q*16 + hi*8
        *(uint2*)(prow + ((c * 64 + q * 16 + hi * 8) ^ pswz)) = d2;
      }
    }
    // P visibility barrier — LDS-only drain, prefetch loads stay in flight
    asm volatile("s_waitcnt lgkmcnt(0)" ::: "memory");
    __builtin_amdgcn_sched_barrier(0);
    __builtin_amdgcn_s_barrier();
    __builtin_amdgcn_sched_barrier(0);

    // ---- PV: wave's 64 qrows x 128 dcols = 2x4 32x32 tiles ----
    const char* vcur = vbuf + cur * 32768;
    const int pr0 = a * 64 + l31;
    const int pr1 = a * 64 + 32 + l31;
    #pragma unroll
    for (int ch = 0; ch < 4; ch++) {
      const int cb = ch * 32 + hi * 16;
      bf16x8 pa0 = *(const bf16x8*)(P + pr0 * 128 + (cb ^ ((pr0 & 7) << 4)));
      bf16x8 pa1 = *(const bf16x8*)(P + pr1 * 128 + (cb ^ ((pr1 & 7) << 4)));
      #pragma unroll
      for (int dt = 0; dt < 4; dt++) {
        int dl = h * 128 + dt * 32 + l31;
        bf16x8 vf = *(const bf16x8*)(vcur + dl * 128 + (cb ^ ((dl & 7) << 4)));
        oacc[0][dt] = __builtin_amdgcn_mfma_f32_32x32x16_bf16(pa0, vf, oacc[0][dt], 0, 0, 0);
        oacc[1][dt] = __builtin_amdgcn_mfma_f32_32x32x16_bf16(pa1, vf, oacc[1][dt], 0, 0, 0);
      }
    }
    // end-of-tile: next buffers staged (single counted drain point per iter)
    asm volatile("s_waitcnt vmcnt(0)" ::: "memory");
    __builtin_amdgcn_sched_barrier(0);
    __builtin_amdgcn_s_barrier();
    __builtin_amdgcn_sched_barrier(0);
  }

  // write numerator partials (fp16). C layout: col=lane&31, row=(r&3)+8*(r>>2)+4*hi
  unsigned short* np = nump + (size_t)split * NROWS * DDIM;
  #pragma unroll
  for (int tt = 0; tt < 2; tt++)
    #pragma unroll
    for (int dt = 0; dt < 4; dt++)
      #pragma unroll
      for (int r = 0; r < 16; r++) {
        int rowg = q0 + a * 64 + tt * 32 + (r & 3) + 8 * (r >> 2) + 4 * hi;
        int col  = h * 128 + dt * 32 + l31;
        np[(size_t)rowg * DDIM + col] = f2h_bits(oacc[tt][dt][r]);
      }
  // den: lanes l and l+32 hold the same qrow's two kcol interleaves
  {
    float d = denl;
    d += __shfl_xor(d, 32);
    if (l < 32)
      denp[(size_t)split * NROWS + q0 + w * 32 + l] = d;
  }
}

// ---------------- kernel 3: combine partials, diagonal fix, output ----------------
__global__ __launch_bounds__(256) void combine_kernel(
    const float* __restrict__ x, const unsigned short* __restrict__ qb,
    const unsigned short* __restrict__ kb, const unsigned short* __restrict__ vb,
    const unsigned short* __restrict__ nump, const float* __restrict__ denp,
    float* __restrict__ out)
{
  const int t = threadIdx.x;
  const int w = t >> 6, l = t & 63;
  const int i = blockIdx.x * 4 + w;

  ushort4 q4 = *(const ushort4*)(qb + (size_t)i * DDIM + l * 4);
  ushort4 k4 = *(const ushort4*)(kb + (size_t)i * DDIM + l * 4);
  float s = bf2f(q4.x) * bf2f(k4.x) + bf2f(q4.y) * bf2f(k4.y)
          + bf2f(q4.z) * bf2f(k4.z) + bf2f(q4.w) * bf2f(k4.w);
  #pragma unroll
  for (int m = 1; m < 64; m <<= 1) s += __shfl_xor(s, m);
  float r  = fmaxf(s, 0.f);
  float rb = bf2f(f2bf_bits(r));   // match attn's bf16-rounded P value

  float den = 0.f;
  #pragma unroll
  for (int sp = 0; sp < KSPLIT; sp++)
    den += denp[(size_t)sp * NROWS + i];
  float inv = 1.f / fmaxf(den - rb, 1e-12f);

  const int d0 = l * 4;
  float4 acc = {0.f, 0.f, 0.f, 0.f};
  #pragma unroll
  for (int sp = 0; sp < KSPLIT; sp++) {
    ushort4 u4 = *(const ushort4*)(nump + ((size_t)sp * NROWS + i) * DDIM + d0);
    acc.x += h2f(u4.x); acc.y += h2f(u4.y);
    acc.z += h2f(u4.z); acc.w += h2f(u4.w);
  }
  ushort4 v4 = *(const ushort4*)(vb + (size_t)i * DDIM + d0);
  float4 xx = *(const float4*)(x + (size_t)i * DDIM + d0);
  float4 o;
  o.x = (acc.x - rb * bf2f(v4.x)) * inv + xx.x;
  o.y = (acc.y - rb * bf2f(v4.y)) * inv + xx.y;
  o.z = (acc.z - rb * bf2f(v4.z)) * inv + xx.z;
  o.w = (acc.w - rb * bf2f(v4.w)) * inv + xx.w;
  *(float4*)(out + (size_t)i * DDIM + d0) = o;
}

extern "C" void kernel_launch(void* const* d_in, const int* in_sizes, int n_in,
                              void* d_out, int out_size, void* d_ws, size_t ws_size,
                              hipStream_t stream)
{
  const float* x  = (const float*)d_in[0];
  const float* Wq = (const float*)d_in[1];
  const float* bq = (const float*)d_in[2];
  const float* Wk = (const float*)d_in[3];
  const float* bk = (const float*)d_in[4];
  const float* Wv = (const float*)d_in[5];
  const float* bv = (const float*)d_in[6];

  char* ws = (char*)d_ws;
  unsigned short* qb  = (unsigned short*)(ws + 0);          // 4 MB
  unsigned short* kb  = (unsigned short*)(ws + 4194304);    // 4 MB
  unsigned short* vb  = (unsigned short*)(ws + 8388608);    // 4 MB
  unsigned short* vT  = (unsigned short*)(ws + 12582912);   // 4 MB
  unsigned short* nump = (unsigned short*)(ws + 16777216);  // 32 MB (8 splits, fp16)
  float* denp = (float*)(ws + 50331648);                    // 256 KB (8 slices)

  qkv_kernel<<<384, 256, 0, stream>>>(bq, bk, bv, x, Wq, Wk, Wv, qb, kb, vb, vT);
  attn_kernel<<<(NROWS / BM) * KSPLIT, 512, 0, stream>>>(qb, kb, vT, nump, denp);
  combine_kernel<<<NROWS / 4, 256, 0, stream>>>(x, qb, kb, vb, nump, denp, (float*)d_out);
}

// Round 8
// 168.559 us; speedup vs baseline: 1.0904x; 1.0904x over previous
//
#include <hip/hip_runtime.h>

#define NROWS 8192
#define DDIM  256
#define KSPLIT 4
#define BM 128
#define BK 64
#define NT (NROWS / KSPLIT / BK)   // 32 tiles per split

typedef __bf16 bf16x8 __attribute__((ext_vector_type(8)));
typedef float  f32x4  __attribute__((ext_vector_type(4)));
typedef float  f32x16 __attribute__((ext_vector_type(16)));

typedef __attribute__((address_space(1))) unsigned int uint_gas;
typedef __attribute__((address_space(3))) unsigned int uint_las;

__device__ __forceinline__ void gload_lds16(const void* g, void* l) {
  __builtin_amdgcn_global_load_lds((const uint_gas*)g, (uint_las*)l, 16, 0, 0);
}

__device__ __forceinline__ unsigned int f2bf_bits(float f) {
  union { float f; unsigned int u; } v; v.f = f;
  unsigned int r = v.u + 0x7FFFu + ((v.u >> 16) & 1u);
  return r >> 16;
}
__device__ __forceinline__ float bf2f(unsigned int b) {
  union { unsigned int u; float f; } v; v.u = b << 16;
  return v.f;
}
__device__ __forceinline__ unsigned int pack2bf(float a, float b) {
  union { unsigned int u; __bf16 h[2]; } p;
  p.h[0] = (__bf16)a; p.h[1] = (__bf16)b;
  return p.u;
}
__device__ __forceinline__ unsigned short f2h_bits(float f) {
  union { _Float16 h; unsigned short u; } c; c.h = (_Float16)f;
  return c.u;
}
__device__ __forceinline__ float h2f(unsigned short u) {
  union { unsigned short u; _Float16 h; } c; c.u = u;
  return (float)c.h;
}

// ---------------- kernel 0: fp32 -> bf16 conversion (x and weights) ----------------
__global__ __launch_bounds__(256) void convert_kernel(
    const float* __restrict__ x, const float* __restrict__ wq,
    const float* __restrict__ wk, const float* __restrict__ wv,
    unsigned short* __restrict__ xb, unsigned short* __restrict__ Wb)
{
  int i = blockIdx.x * 256 + threadIdx.x;
  const int nx4 = NROWS * DDIM / 4;
  const int nw4 = DDIM * DDIM / 4;
  const float4* src; unsigned short* dst; int j;
  if (i < nx4)              { src = (const float4*)x;  dst = xb;                j = i; }
  else if (i < nx4 +   nw4) { src = (const float4*)wq; dst = Wb;                j = i - nx4; }
  else if (i < nx4 + 2*nw4) { src = (const float4*)wk; dst = Wb + DDIM*DDIM;    j = i - nx4 - nw4; }
  else                      { src = (const float4*)wv; dst = Wb + 2*DDIM*DDIM;  j = i - nx4 - 2*nw4; }
  float4 f = src[j];
  ushort4 o;
  o.x = (unsigned short)f2bf_bits(f.x);
  o.y = (unsigned short)f2bf_bits(f.y);
  o.z = (unsigned short)f2bf_bits(f.z);
  o.w = (unsigned short)f2bf_bits(f.w);
  ((ushort4*)dst)[j] = o;
}

// ---------------- kernel 1: QKV projections + L2 norm + vT ----------------
// grid = 384: out = bid/128 (0=q,1=k,2=v), mb = bid%128 (64-row slab)
__global__ __launch_bounds__(256) void qkv_kernel(
    const float* __restrict__ bq, const float* __restrict__ bk, const float* __restrict__ bv,
    const unsigned short* __restrict__ xb, const unsigned short* __restrict__ Wb,
    unsigned short* __restrict__ qb, unsigned short* __restrict__ kb,
    unsigned short* __restrict__ vb, unsigned short* __restrict__ vT)
{
  __shared__ unsigned short vstage[DDIM * 72];
  const int t = threadIdx.x;
  const int w = t >> 6, l = t & 63;
  const int c = l & 15, g = l >> 4;
  const int out = blockIdx.x / 128;
  const int mb  = blockIdx.x % 128;
  const int row0 = mb * 64;
  const int rw = row0 + w * 16;

  bf16x8 a[8];
  #pragma unroll
  for (int ks = 0; ks < 8; ks++)
    a[ks] = *(const bf16x8*)(xb + (size_t)(rw + c) * DDIM + ks * 32 + g * 8);

  const unsigned short* W = Wb + out * DDIM * DDIM;
  const float* bias = (out == 0) ? bq : (out == 1) ? bk : bv;
  unsigned short* dst = (out == 0) ? qb : (out == 1) ? kb : vb;
  f32x4 vals[16];
  #pragma unroll
  for (int ct = 0; ct < 16; ct++) {
    f32x4 acc = {0.f, 0.f, 0.f, 0.f};
    #pragma unroll
    for (int ks = 0; ks < 8; ks++) {
      bf16x8 b = *(const bf16x8*)(W + (size_t)(ct * 16 + c) * DDIM + ks * 32 + g * 8);
      acc = __builtin_amdgcn_mfma_f32_16x16x32_bf16(a[ks], b, acc, 0, 0, 0);
    }
    float bias_v = bias[ct * 16 + c];
    #pragma unroll
    for (int r = 0; r < 4; r++) acc[r] += bias_v;
    vals[ct] = acc;
  }
  if (out < 2) {   // L2 normalize rows (q, k)
    #pragma unroll
    for (int r = 0; r < 4; r++) {
      float ss = 0.f;
      #pragma unroll
      for (int ct = 0; ct < 16; ct++) ss += vals[ct][r] * vals[ct][r];
      ss += __shfl_xor(ss, 1); ss += __shfl_xor(ss, 2);
      ss += __shfl_xor(ss, 4); ss += __shfl_xor(ss, 8);
      float inv = 1.f / fmaxf(sqrtf(ss), 1e-12f);
      #pragma unroll
      for (int ct = 0; ct < 16; ct++) vals[ct][r] *= inv;
    }
  }
  #pragma unroll
  for (int ct = 0; ct < 16; ct++) {
    #pragma unroll
    for (int r = 0; r < 4; r++) {
      unsigned int bits = f2bf_bits(vals[ct][r]);
      unsigned int ob = (unsigned int)__shfl_xor((int)bits, 1);
      if (!(l & 1))
        *(unsigned int*)(dst + (size_t)(rw + g * 4 + r) * DDIM + ct * 16 + c) =
            bits | (ob << 16);
      if (out == 2)
        vstage[(ct * 16 + c) * 72 + (w * 16 + g * 4 + r)] = (unsigned short)bits;
    }
  }
  if (out == 2) {
    __syncthreads();
    #pragma unroll
    for (int p = 0; p < 8; p++) {
      int dd = (t >> 3) + p * 32;
      int ch = t & 7;
      *(uint4*)(vT + (size_t)dd * NROWS + row0 + ch * 8) =
          *(const uint4*)(vstage + dd * 72 + ch * 8);
    }
  }
}

// ---------------- kernel 2: fused relu-attention partials (32x32x16 MFMA) ----------------
// BM=128, 8 waves. S: 4(qrow32) x 2(kcol32), swapped mfma(K,Q) -> S^T, lane&31 = qrow,
// per-lane den, cvt_pk pack to P-LDS. PV: 2(qrow64) x 4(dcol64), 2x2 32x32 tiles;
// vf loaded DIRECTLY from global vT (L2-resident) — V never staged in LDS.
__global__ __launch_bounds__(512, 2) void attn_kernel(
    const unsigned short* __restrict__ qb, const unsigned short* __restrict__ kb,
    const unsigned short* __restrict__ vT,
    unsigned short* __restrict__ nump, float* __restrict__ denp)
{
  // 2x32KB K dbuf | 16KB P ([128][64] bf16, XOR-swizzled)
  __shared__ __align__(16) char smem[81920];
  char* kbuf = smem;
  char* P    = smem + 65536;

  const int t = threadIdx.x;
  const int w = t >> 6, l = t & 63;
  const int l31 = l & 31, hi = l >> 5;
  const int sr = w >> 1, sc = w & 1;   // S-phase
  const int pr = w >> 2, pc = w & 3;   // PV-phase
  const int bid = blockIdx.x;
  const int split = bid & (KSPLIT - 1);
  const int mb = bid >> 2;
  const int q0 = mb * BM;
  const int kbase0 = split * (NROWS / KSPLIT);

  const char* kbc = (const char*)kb;
  const char* vtc = (const char*)vT;

  // hoist q fragments: lane&31 = qrow, 16 K-chunks = 64 VGPR
  bf16x8 qa[16];
  {
    const unsigned short* qrowp = qb + (size_t)(q0 + sr * 32 + l31) * DDIM + hi * 8;
    #pragma unroll
    for (int m = 0; m < 16; m++)
      qa[m] = *(const bf16x8*)(qrowp + m * 16);
  }

  f32x16 oacc[2][2];
  #pragma unroll
  for (int rt = 0; rt < 2; rt++)
    #pragma unroll
    for (int dt = 0; dt < 2; dt++)
      oacc[rt][dt] = (f32x16){0.f};
  float denl = 0.f;

  auto stage = [&](int buf, int it) {
    const int kbase = kbase0 + it * BK;
    const char* ksrc = kbc + (size_t)kbase * 512;
    #pragma unroll
    for (int i = 0; i < 4; i++) {
      int n = i * 512 + t;
      int row = n >> 5, slot = n & 31;
      gload_lds16(ksrc + row * 512 + ((slot ^ (row & 7)) * 16),
                  kbuf + buf * 32768 + i * 8192 + w * 1024);
    }
  };

  // prologue: stage K tile 0 into buf 0
  stage(0, 0);
  asm volatile("s_waitcnt vmcnt(0)" ::: "memory");
  __builtin_amdgcn_sched_barrier(0);
  __builtin_amdgcn_s_barrier();
  __builtin_amdgcn_sched_barrier(0);

  for (int it = 0; it < NT; ++it) {
    const int cur = it & 1;
    const int kbase = kbase0 + it * BK;

    // issue vf global loads for THIS iter (latency hidden under S-phase)
    bf16x8 vf[2][4];
    #pragma unroll
    for (int dt = 0; dt < 2; dt++) {
      const int dl = pc * 64 + dt * 32 + l31;
      #pragma unroll
      for (int ch = 0; ch < 4; ch++)
        vf[dt][ch] = *(const bf16x8*)(vtc +
            ((size_t)dl * NROWS + kbase + ch * 16 + hi * 8) * 2);
    }
    // issue next K-tile prefetch
    if (it + 1 < NT) stage(cur ^ 1, it + 1);
    __builtin_amdgcn_sched_barrier(0);

    // ---- S^T = K.Q^T: wave's 32 kcols x 32 qrows ----
    const char* kcur = kbuf + cur * 32768;
    const int krl = sc * 32 + l31;
    const int kswz = (krl & 7) << 4;
    f32x16 sacc = (f32x16){0.f};
    #pragma unroll
    for (int m = 0; m < 16; m++) {
      bf16x8 kf = *(const bf16x8*)(kcur + krl * 512 + ((m * 32 + hi * 16) ^ kswz));
      sacc = __builtin_amdgcn_mfma_f32_32x32x16_bf16(kf, qa[m], sacc, 0, 0, 0);
    }
    // relu + per-lane den + in-lane bf16 pack to P
    {
      const int qrow = sr * 32 + l31;
      char* prow = P + qrow * 128;
      const int pswz = (qrow & 7) << 4;
      #pragma unroll
      for (int q = 0; q < 4; q++) {
        float v0 = fmaxf(sacc[4 * q + 0], 0.f);
        float v1 = fmaxf(sacc[4 * q + 1], 0.f);
        float v2 = fmaxf(sacc[4 * q + 2], 0.f);
        float v3 = fmaxf(sacc[4 * q + 3], 0.f);
        denl += (v0 + v1) + (v2 + v3);
        uint2 d2;
        d2.x = pack2bf(v0, v1);
        d2.y = pack2bf(v2, v3);
        *(uint2*)(prow + ((sc * 64 + q * 16 + hi * 8) ^ pswz)) = d2;
      }
    }
    // P visibility barrier — LDS-only drain, prefetch + vf loads stay in flight
    asm volatile("s_waitcnt lgkmcnt(0)" ::: "memory");
    __builtin_amdgcn_sched_barrier(0);
    __builtin_amdgcn_s_barrier();
    __builtin_amdgcn_sched_barrier(0);

    // ---- PV: wave's 64 qrows x 64 dcols as 2x2 32x32 tiles ----
    const int pr0 = pr * 64 + l31;
    const int pr1 = pr * 64 + 32 + l31;
    #pragma unroll
    for (int ch = 0; ch < 4; ch++) {
      const int cb = ch * 32 + hi * 16;
      bf16x8 pa0 = *(const bf16x8*)(P + pr0 * 128 + (cb ^ ((pr0 & 7) << 4)));
      bf16x8 pa1 = *(const bf16x8*)(P + pr1 * 128 + (cb ^ ((pr1 & 7) << 4)));
      #pragma unroll
      for (int dt = 0; dt < 2; dt++) {
        oacc[0][dt] = __builtin_amdgcn_mfma_f32_32x32x16_bf16(pa0, vf[dt][ch], oacc[0][dt], 0, 0, 0);
        oacc[1][dt] = __builtin_amdgcn_mfma_f32_32x32x16_bf16(pa1, vf[dt][ch], oacc[1][dt], 0, 0, 0);
      }
    }
    // end-of-tile: K prefetch staged (single counted drain point per iter)
    asm volatile("s_waitcnt vmcnt(0)" ::: "memory");
    __builtin_amdgcn_sched_barrier(0);
    __builtin_amdgcn_s_barrier();
    __builtin_amdgcn_sched_barrier(0);
  }

  // write numerator partials (fp16). C layout: col=lane&31, row=(r&3)+8*(r>>2)+4*hi
  unsigned short* np = nump + (size_t)split * NROWS * DDIM;
  #pragma unroll
  for (int rt = 0; rt < 2; rt++)
    #pragma unroll
    for (int dt = 0; dt < 2; dt++)
      #pragma unroll
      for (int r = 0; r < 16; r++) {
        int rowg = q0 + pr * 64 + rt * 32 + (r & 3) + 8 * (r >> 2) + 4 * hi;
        int col  = pc * 64 + dt * 32 + l31;
        np[(size_t)rowg * DDIM + col] = f2h_bits(oacc[rt][dt][r]);
      }
  // den: lanes l and l+32 hold the same qrow's two kcol interleaves
  {
    float d = denl;
    d += __shfl_xor(d, 32);
    if (l < 32)
      denp[((size_t)split * 2 + sc) * NROWS + q0 + sr * 32 + l] = d;
  }
}

// ---------------- kernel 3: combine partials, diagonal fix, output ----------------
__global__ __launch_bounds__(256) void combine_kernel(
    const float* __restrict__ x, const unsigned short* __restrict__ qb,
    const unsigned short* __restrict__ kb, const unsigned short* __restrict__ vb,
    const unsigned short* __restrict__ nump, const float* __restrict__ denp,
    float* __restrict__ out)
{
  const int t = threadIdx.x;
  const int w = t >> 6, l = t & 63;
  const int i = blockIdx.x * 4 + w;

  ushort4 q4 = *(const ushort4*)(qb + (size_t)i * DDIM + l * 4);
  ushort4 k4 = *(const ushort4*)(kb + (size_t)i * DDIM + l * 4);
  float s = bf2f(q4.x) * bf2f(k4.x) + bf2f(q4.y) * bf2f(k4.y)
          + bf2f(q4.z) * bf2f(k4.z) + bf2f(q4.w) * bf2f(k4.w);
  #pragma unroll
  for (int m = 1; m < 64; m <<= 1) s += __shfl_xor(s, m);
  float r  = fmaxf(s, 0.f);
  float rb = bf2f(f2bf_bits(r));   // match attn's bf16-rounded P value

  float den = 0.f;
  #pragma unroll
  for (int sp = 0; sp < KSPLIT * 2; sp++)
    den += denp[(size_t)sp * NROWS + i];
  float inv = 1.f / fmaxf(den - rb, 1e-12f);

  const int d0 = l * 4;
  float4 acc = {0.f, 0.f, 0.f, 0.f};
  #pragma unroll
  for (int sp = 0; sp < KSPLIT; sp++) {
    ushort4 u4 = *(const ushort4*)(nump + ((size_t)sp * NROWS + i) * DDIM + d0);
    acc.x += h2f(u4.x); acc.y += h2f(u4.y);
    acc.z += h2f(u4.z); acc.w += h2f(u4.w);
  }
  ushort4 v4 = *(const ushort4*)(vb + (size_t)i * DDIM + d0);
  float4 xx = *(const float4*)(x + (size_t)i * DDIM + d0);
  float4 o;
  o.x = (acc.x - rb * bf2f(v4.x)) * inv + xx.x;
  o.y = (acc.y - rb * bf2f(v4.y)) * inv + xx.y;
  o.z = (acc.z - rb * bf2f(v4.z)) * inv + xx.z;
  o.w = (acc.w - rb * bf2f(v4.w)) * inv + xx.w;
  *(float4*)(out + (size_t)i * DDIM + d0) = o;
}

extern "C" void kernel_launch(void* const* d_in, const int* in_sizes, int n_in,
                              void* d_out, int out_size, void* d_ws, size_t ws_size,
                              hipStream_t stream)
{
  const float* x  = (const float*)d_in[0];
  const float* Wq = (const float*)d_in[1];
  const float* bq = (const float*)d_in[2];
  const float* Wk = (const float*)d_in[3];
  const float* bk = (const float*)d_in[4];
  const float* Wv = (const float*)d_in[5];
  const float* bv = (const float*)d_in[6];

  char* ws = (char*)d_ws;
  unsigned short* xb   = (unsigned short*)(ws + 0);          // 4 MB
  unsigned short* Wb   = (unsigned short*)(ws + 4194304);    // 384 KB
  unsigned short* qb   = (unsigned short*)(ws + 4587520);    // 4 MB
  unsigned short* kb   = (unsigned short*)(ws + 8781824);    // 4 MB
  unsigned short* vb   = (unsigned short*)(ws + 12976128);   // 4 MB
  unsigned short* vT   = (unsigned short*)(ws + 17170432);   // 4 MB
  unsigned short* nump = (unsigned short*)(ws + 21364736);   // 16 MB (4 splits, fp16)
  float* denp = (float*)(ws + 38141952);                     // 256 KB (8 slices)

  convert_kernel<<<2240, 256, 0, stream>>>(x, Wq, Wk, Wv, xb, Wb);
  qkv_kernel<<<384, 256, 0, stream>>>(bq, bk, bv, xb, Wb, qb, kb, vb, vT);
  attn_kernel<<<(NROWS / BM) * KSPLIT, 512, 0, stream>>>(qb, kb, vT, nump, denp);
  combine_kernel<<<NROWS / 4, 256, 0, stream>>>(x, qb, kb, vb, nump, denp, (float*)d_out);
}

// Round 9
// 126.246 us; speedup vs baseline: 1.4559x; 1.3352x over previous
//
#include <hip/hip_runtime.h>

#define NROWS 8192
#define DDIM  256
#define KSPLIT 4
#define BM 128
#define BK 64
#define NT (NROWS / KSPLIT / BK)   // 32 tiles per split

typedef __bf16 bf16x8 __attribute__((ext_vector_type(8)));
typedef float  f32x4  __attribute__((ext_vector_type(4)));
typedef float  f32x16 __attribute__((ext_vector_type(16)));

typedef __attribute__((address_space(1))) unsigned int uint_gas;
typedef __attribute__((address_space(3))) unsigned int uint_las;

__device__ __forceinline__ void gload_lds16(const void* g, void* l) {
  __builtin_amdgcn_global_load_lds((const uint_gas*)g, (uint_las*)l, 16, 0, 0);
}

__device__ __forceinline__ unsigned int f2bf_bits(float f) {
  union { float f; unsigned int u; } v; v.f = f;
  unsigned int r = v.u + 0x7FFFu + ((v.u >> 16) & 1u);
  return r >> 16;
}
__device__ __forceinline__ float bf2f(unsigned int b) {
  union { unsigned int u; float f; } v; v.u = b << 16;
  return v.f;
}
__device__ __forceinline__ unsigned int pack2bf(float a, float b) {
  union { unsigned int u; __bf16 h[2]; } p;
  p.h[0] = (__bf16)a; p.h[1] = (__bf16)b;
  return p.u;
}
__device__ __forceinline__ unsigned short f2h_bits(float f) {
  union { _Float16 h; unsigned short u; } c; c.h = (_Float16)f;
  return c.u;
}
__device__ __forceinline__ float h2f(unsigned short u) {
  union { unsigned short u; _Float16 h; } c; c.u = u;
  return (float)c.h;
}

// ---------------- kernel 0: fp32 -> bf16 conversion (x and weights) ----------------
__global__ __launch_bounds__(256) void convert_kernel(
    const float* __restrict__ x, const float* __restrict__ wq,
    const float* __restrict__ wk, const float* __restrict__ wv,
    unsigned short* __restrict__ xb, unsigned short* __restrict__ Wb)
{
  int i = blockIdx.x * 256 + threadIdx.x;
  const int nx4 = NROWS * DDIM / 4;
  const int nw4 = DDIM * DDIM / 4;
  const float4* src; unsigned short* dst; int j;
  if (i < nx4)              { src = (const float4*)x;  dst = xb;                j = i; }
  else if (i < nx4 +   nw4) { src = (const float4*)wq; dst = Wb;                j = i - nx4; }
  else if (i < nx4 + 2*nw4) { src = (const float4*)wk; dst = Wb + DDIM*DDIM;    j = i - nx4 - nw4; }
  else                      { src = (const float4*)wv; dst = Wb + 2*DDIM*DDIM;  j = i - nx4 - 2*nw4; }
  float4 f = src[j];
  ushort4 o;
  o.x = (unsigned short)f2bf_bits(f.x);
  o.y = (unsigned short)f2bf_bits(f.y);
  o.z = (unsigned short)f2bf_bits(f.z);
  o.w = (unsigned short)f2bf_bits(f.w);
  ((ushort4*)dst)[j] = o;
}

// ---------------- kernel 1: QKV projections + L2 norm + vT ----------------
// grid = 384: out = bid/128 (0=q,1=k,2=v), mb = bid%128 (64-row slab)
__global__ __launch_bounds__(256) void qkv_kernel(
    const float* __restrict__ bq, const float* __restrict__ bk, const float* __restrict__ bv,
    const unsigned short* __restrict__ xb, const unsigned short* __restrict__ Wb,
    unsigned short* __restrict__ qb, unsigned short* __restrict__ kb,
    unsigned short* __restrict__ vb, unsigned short* __restrict__ vT)
{
  __shared__ unsigned short vstage[DDIM * 72];
  const int t = threadIdx.x;
  const int w = t >> 6, l = t & 63;
  const int c = l & 15, g = l >> 4;
  const int out = blockIdx.x / 128;
  const int mb  = blockIdx.x % 128;
  const int row0 = mb * 64;
  const int rw = row0 + w * 16;

  bf16x8 a[8];
  #pragma unroll
  for (int ks = 0; ks < 8; ks++)
    a[ks] = *(const bf16x8*)(xb + (size_t)(rw + c) * DDIM + ks * 32 + g * 8);

  const unsigned short* W = Wb + out * DDIM * DDIM;
  const float* bias = (out == 0) ? bq : (out == 1) ? bk : bv;
  unsigned short* dst = (out == 0) ? qb : (out == 1) ? kb : vb;
  f32x4 vals[16];
  #pragma unroll
  for (int ct = 0; ct < 16; ct++) {
    f32x4 acc = {0.f, 0.f, 0.f, 0.f};
    #pragma unroll
    for (int ks = 0; ks < 8; ks++) {
      bf16x8 b = *(const bf16x8*)(W + (size_t)(ct * 16 + c) * DDIM + ks * 32 + g * 8);
      acc = __builtin_amdgcn_mfma_f32_16x16x32_bf16(a[ks], b, acc, 0, 0, 0);
    }
    float bias_v = bias[ct * 16 + c];
    #pragma unroll
    for (int r = 0; r < 4; r++) acc[r] += bias_v;
    vals[ct] = acc;
  }
  if (out < 2) {   // L2 normalize rows (q, k)
    #pragma unroll
    for (int r = 0; r < 4; r++) {
      float ss = 0.f;
      #pragma unroll
      for (int ct = 0; ct < 16; ct++) ss += vals[ct][r] * vals[ct][r];
      ss += __shfl_xor(ss, 1); ss += __shfl_xor(ss, 2);
      ss += __shfl_xor(ss, 4); ss += __shfl_xor(ss, 8);
      float inv = 1.f / fmaxf(sqrtf(ss), 1e-12f);
      #pragma unroll
      for (int ct = 0; ct < 16; ct++) vals[ct][r] *= inv;
    }
  }
  #pragma unroll
  for (int ct = 0; ct < 16; ct++) {
    #pragma unroll
    for (int r = 0; r < 4; r++) {
      unsigned int bits = f2bf_bits(vals[ct][r]);
      unsigned int ob = (unsigned int)__shfl_xor((int)bits, 1);
      if (!(l & 1))
        *(unsigned int*)(dst + (size_t)(rw + g * 4 + r) * DDIM + ct * 16 + c) =
            bits | (ob << 16);
      if (out == 2)
        vstage[(ct * 16 + c) * 72 + (w * 16 + g * 4 + r)] = (unsigned short)bits;
    }
  }
  if (out == 2) {
    __syncthreads();
    #pragma unroll
    for (int p = 0; p < 8; p++) {
      int dd = (t >> 3) + p * 32;
      int ch = t & 7;
      *(uint4*)(vT + (size_t)dd * NROWS + row0 + ch * 8) =
          *(const uint4*)(vstage + dd * 72 + ch * 8);
    }
  }
}

// ---------------- kernel 2: fused relu-attention, cross-phase pipelined ----------------
// BM=128, 8 waves. Region(t) = { S(t): kf(kbuf[cur], rotation-swz) -> sacc -> P(Pb[cur]) }
//                 ∥ { PV(t-1): pa(Pb[cur^1]) x vf(vbuf[cur^1]) -> oacc }  — one sched region,
// LDS reads of one stream hide under MFMAs of the other. K rotation swizzle: 32-slot
// conflict-free. P/vT keep XOR-8. LDS = 2x32K(K) + 2x32K(vT) + 2x16K(P) = 160 KB.
__global__ __launch_bounds__(512, 2) void attn_kernel(
    const unsigned short* __restrict__ qb, const unsigned short* __restrict__ kb,
    const unsigned short* __restrict__ vT,
    unsigned short* __restrict__ nump, float* __restrict__ denp)
{
  __shared__ __align__(16) char smem[163840];
  char* kbuf = smem;            // [2][32768]
  char* vbuf = smem + 65536;    // [2][32768]
  char* Pb   = smem + 131072;   // [2][16384]

  const int t = threadIdx.x;
  const int w = t >> 6, l = t & 63;
  const int l31 = l & 31, hi = l >> 5;
  const int sr = w >> 1, sc = w & 1;   // S-phase: qrow32 group, kcol32 half
  const int pr = w >> 2, pc = w & 3;   // PV-phase: qrow64 group, dcol64 group
  const int bid = blockIdx.x;
  const int split = bid & (KSPLIT - 1);
  const int mb = bid >> 2;
  const int q0 = mb * BM;
  const int kbase0 = split * (NROWS / KSPLIT);

  const char* kbc = (const char*)kb;
  const char* vtc = (const char*)vT;

  // hoist q fragments: lane&31 = qrow, 16 K-chunks = 64 VGPR
  bf16x8 qa[16];
  {
    const unsigned short* qrowp = qb + (size_t)(q0 + sr * 32 + l31) * DDIM + hi * 8;
    #pragma unroll
    for (int m = 0; m < 16; m++)
      qa[m] = *(const bf16x8*)(qrowp + m * 16);
  }

  f32x16 oacc[2][2];
  #pragma unroll
  for (int rt = 0; rt < 2; rt++)
    #pragma unroll
    for (int dt = 0; dt < 2; dt++)
      oacc[rt][dt] = (f32x16){0.f};
  float denl = 0.f;

  // K stage: rotation swizzle — lds[row][slot] = K[row][(slot-row)&31]
  auto stageK = [&](int buf, int it) {
    const int kbase = kbase0 + it * BK;
    const char* ksrc = kbc + (size_t)kbase * 512;
    #pragma unroll
    for (int i = 0; i < 4; i++) {
      int n = i * 512 + t;
      int row = n >> 5, slot = n & 31;
      gload_lds16(ksrc + row * 512 + (((slot - row) & 31) << 4),
                  kbuf + buf * 32768 + i * 8192 + w * 1024);
    }
  };
  // vT stage: XOR-8 swizzle — lds[d][slot] = vT[d][slot ^ (d&7)]
  auto stageV = [&](int buf, int it) {
    const int kbase = kbase0 + it * BK;
    const char* vsrc = vtc + (size_t)kbase * 2;
    #pragma unroll
    for (int i = 0; i < 4; i++) {
      int n = i * 512 + t;
      int dd = n >> 3, slot = n & 7;
      gload_lds16(vsrc + (size_t)dd * (NROWS * 2) + ((slot ^ (dd & 7)) * 16),
                  vbuf + buf * 32768 + i * 8192 + w * 1024);
    }
  };

  // prologue: stage K(0)
  stageK(0, 0);
  asm volatile("s_waitcnt vmcnt(0)" ::: "memory");
  __builtin_amdgcn_sched_barrier(0);
  __builtin_amdgcn_s_barrier();
  __builtin_amdgcn_sched_barrier(0);

  const int qrow = sr * 32 + l31;
  char* prowP = (char*)0;  // set per iter (Pb dbuf)
  const int pswz = (qrow & 7) << 4;
  const int krl = sc * 32 + l31;

  for (int it = 0; it < NT; ++it) {
    const int cur = it & 1;
    // issue next K tile + this iter's vT tile (consumed by PV next iter)
    if (it + 1 < NT) stageK(cur ^ 1, it + 1);
    stageV(cur, it);
    __builtin_amdgcn_sched_barrier(0);

    // ================= REGION: S(it) ∥ PV(it-1) =================
    // ---- S(it): wave's 32 kcols x 32 qrows, rotation-swz kf ----
    const char* kcur = kbuf + cur * 32768;
    f32x16 sacc = (f32x16){0.f};
    #pragma unroll
    for (int m = 0; m < 16; m++) {
      bf16x8 kf = *(const bf16x8*)(kcur + krl * 512 +
                                   (((m * 2 + hi + krl) & 31) << 4));
      sacc = __builtin_amdgcn_mfma_f32_32x32x16_bf16(kf, qa[m], sacc, 0, 0, 0);
    }
    // relu + per-lane den + pack to Pb[cur]
    prowP = Pb + cur * 16384 + qrow * 128;
    #pragma unroll
    for (int q = 0; q < 4; q++) {
      float v0 = fmaxf(sacc[4 * q + 0], 0.f);
      float v1 = fmaxf(sacc[4 * q + 1], 0.f);
      float v2 = fmaxf(sacc[4 * q + 2], 0.f);
      float v3 = fmaxf(sacc[4 * q + 3], 0.f);
      denl += (v0 + v1) + (v2 + v3);
      uint2 d2;
      d2.x = pack2bf(v0, v1);
      d2.y = pack2bf(v2, v3);
      *(uint2*)(prowP + ((sc * 64 + q * 16 + hi * 8) ^ pswz)) = d2;
    }

    // ---- PV(it-1): pa from Pb[cur^1], vf from vbuf[cur^1] ----
    if (it > 0) {
      const char* Pprev = Pb + (cur ^ 1) * 16384;
      const char* vcur  = vbuf + (cur ^ 1) * 32768;
      const int pr0 = pr * 64 + l31;
      const int pr1 = pr * 64 + 32 + l31;
      #pragma unroll
      for (int ch = 0; ch < 4; ch++) {
        const int cb = ch * 32 + hi * 16;
        bf16x8 pa0 = *(const bf16x8*)(Pprev + pr0 * 128 + (cb ^ ((pr0 & 7) << 4)));
        bf16x8 pa1 = *(const bf16x8*)(Pprev + pr1 * 128 + (cb ^ ((pr1 & 7) << 4)));
        #pragma unroll
        for (int dt = 0; dt < 2; dt++) {
          int dl = pc * 64 + dt * 32 + l31;
          bf16x8 vf = *(const bf16x8*)(vcur + dl * 128 + (cb ^ ((dl & 7) << 4)));
          oacc[0][dt] = __builtin_amdgcn_mfma_f32_32x32x16_bf16(pa0, vf, oacc[0][dt], 0, 0, 0);
          oacc[1][dt] = __builtin_amdgcn_mfma_f32_32x32x16_bf16(pa1, vf, oacc[1][dt], 0, 0, 0);
        }
      }
    }
    // ============================================================
    asm volatile("s_waitcnt lgkmcnt(0)" ::: "memory");
    __builtin_amdgcn_sched_barrier(0);
    asm volatile("s_waitcnt vmcnt(0)" ::: "memory");
    __builtin_amdgcn_sched_barrier(0);
    __builtin_amdgcn_s_barrier();
    __builtin_amdgcn_sched_barrier(0);
  }

  // epilogue: PV(NT-1) — buffers drained and barrier'd at loop end
  {
    const int last = (NT - 1) & 1;
    const char* Pprev = Pb + last * 16384;
    const char* vcur  = vbuf + last * 32768;
    const int pr0 = pr * 64 + l31;
    const int pr1 = pr * 64 + 32 + l31;
    #pragma unroll
    for (int ch = 0; ch < 4; ch++) {
      const int cb = ch * 32 + hi * 16;
      bf16x8 pa0 = *(const bf16x8*)(Pprev + pr0 * 128 + (cb ^ ((pr0 & 7) << 4)));
      bf16x8 pa1 = *(const bf16x8*)(Pprev + pr1 * 128 + (cb ^ ((pr1 & 7) << 4)));
      #pragma unroll
      for (int dt = 0; dt < 2; dt++) {
        int dl = pc * 64 + dt * 32 + l31;
        bf16x8 vf = *(const bf16x8*)(vcur + dl * 128 + (cb ^ ((dl & 7) << 4)));
        oacc[0][dt] = __builtin_amdgcn_mfma_f32_32x32x16_bf16(pa0, vf, oacc[0][dt], 0, 0, 0);
        oacc[1][dt] = __builtin_amdgcn_mfma_f32_32x32x16_bf16(pa1, vf, oacc[1][dt], 0, 0, 0);
      }
    }
  }

  // write numerator partials (fp16). C layout: col=lane&31, row=(r&3)+8*(r>>2)+4*hi
  unsigned short* np = nump + (size_t)split * NROWS * DDIM;
  #pragma unroll
  for (int rt = 0; rt < 2; rt++)
    #pragma unroll
    for (int dt = 0; dt < 2; dt++)
      #pragma unroll
      for (int r = 0; r < 16; r++) {
        int rowg = q0 + pr * 64 + rt * 32 + (r & 3) + 8 * (r >> 2) + 4 * hi;
        int col  = pc * 64 + dt * 32 + l31;
        np[(size_t)rowg * DDIM + col] = f2h_bits(oacc[rt][dt][r]);
      }
  // den: lanes l and l+32 hold the same qrow's two kcol interleaves
  {
    float d = denl;
    d += __shfl_xor(d, 32);
    if (l < 32)
      denp[((size_t)split * 2 + sc) * NROWS + q0 + sr * 32 + l] = d;
  }
}

// ---------------- kernel 3: combine partials, diagonal fix, output ----------------
__global__ __launch_bounds__(256) void combine_kernel(
    const float* __restrict__ x, const unsigned short* __restrict__ qb,
    const unsigned short* __restrict__ kb, const unsigned short* __restrict__ vb,
    const unsigned short* __restrict__ nump, const float* __restrict__ denp,
    float* __restrict__ out)
{
  const int t = threadIdx.x;
  const int w = t >> 6, l = t & 63;
  const int i = blockIdx.x * 4 + w;

  ushort4 q4 = *(const ushort4*)(qb + (size_t)i * DDIM + l * 4);
  ushort4 k4 = *(const ushort4*)(kb + (size_t)i * DDIM + l * 4);
  float s = bf2f(q4.x) * bf2f(k4.x) + bf2f(q4.y) * bf2f(k4.y)
          + bf2f(q4.z) * bf2f(k4.z) + bf2f(q4.w) * bf2f(k4.w);
  #pragma unroll
  for (int m = 1; m < 64; m <<= 1) s += __shfl_xor(s, m);
  float r  = fmaxf(s, 0.f);
  float rb = bf2f(f2bf_bits(r));   // match attn's bf16-rounded P value

  float den = 0.f;
  #pragma unroll
  for (int sp = 0; sp < KSPLIT * 2; sp++)
    den += denp[(size_t)sp * NROWS + i];
  float inv = 1.f / fmaxf(den - rb, 1e-12f);

  const int d0 = l * 4;
  float4 acc = {0.f, 0.f, 0.f, 0.f};
  #pragma unroll
  for (int sp = 0; sp < KSPLIT; sp++) {
    ushort4 u4 = *(const ushort4*)(nump + ((size_t)sp * NROWS + i) * DDIM + d0);
    acc.x += h2f(u4.x); acc.y += h2f(u4.y);
    acc.z += h2f(u4.z); acc.w += h2f(u4.w);
  }
  ushort4 v4 = *(const ushort4*)(vb + (size_t)i * DDIM + d0);
  float4 xx = *(const float4*)(x + (size_t)i * DDIM + d0);
  float4 o;
  o.x = (acc.x - rb * bf2f(v4.x)) * inv + xx.x;
  o.y = (acc.y - rb * bf2f(v4.y)) * inv + xx.y;
  o.z = (acc.z - rb * bf2f(v4.z)) * inv + xx.z;
  o.w = (acc.w - rb * bf2f(v4.w)) * inv + xx.w;
  *(float4*)(out + (size_t)i * DDIM + d0) = o;
}

extern "C" void kernel_launch(void* const* d_in, const int* in_sizes, int n_in,
                              void* d_out, int out_size, void* d_ws, size_t ws_size,
                              hipStream_t stream)
{
  const float* x  = (const float*)d_in[0];
  const float* Wq = (const float*)d_in[1];
  const float* bq = (const float*)d_in[2];
  const float* Wk = (const float*)d_in[3];
  const float* bk = (const float*)d_in[4];
  const float* Wv = (const float*)d_in[5];
  const float* bv = (const float*)d_in[6];

  char* ws = (char*)d_ws;
  unsigned short* xb   = (unsigned short*)(ws + 0);          // 4 MB
  unsigned short* Wb   = (unsigned short*)(ws + 4194304);    // 384 KB
  unsigned short* qb   = (unsigned short*)(ws + 4587520);    // 4 MB
  unsigned short* kb   = (unsigned short*)(ws + 8781824);    // 4 MB
  unsigned short* vb   = (unsigned short*)(ws + 12976128);   // 4 MB
  unsigned short* vT   = (unsigned short*)(ws + 17170432);   // 4 MB
  unsigned short* nump = (unsigned short*)(ws + 21364736);   // 16 MB (4 splits, fp16)
  float* denp = (float*)(ws + 38141952);                     // 256 KB (8 slices)

  convert_kernel<<<2240, 256, 0, stream>>>(x, Wq, Wk, Wv, xb, Wb);
  qkv_kernel<<<384, 256, 0, stream>>>(bq, bk, bv, xb, Wb, qb, kb, vb, vT);
  attn_kernel<<<(NROWS / BM) * KSPLIT, 512, 0, stream>>>(qb, kb, vT, nump, denp);
  combine_kernel<<<NROWS / 4, 256, 0, stream>>>(x, qb, kb, vb, nump, denp, (float*)d_out);
}

// Round 10
// 125.955 us; speedup vs baseline: 1.4592x; 1.0023x over previous
//
#include <hip/hip_runtime.h>

#define NROWS 8192
#define DDIM  256
#define KSPLIT 4
#define BM 128
#define BK 64
#define NT (NROWS / KSPLIT / BK)   // 32 tiles per split

typedef __bf16 bf16x8 __attribute__((ext_vector_type(8)));
typedef float  f32x4  __attribute__((ext_vector_type(4)));
typedef float  f32x16 __attribute__((ext_vector_type(16)));

typedef __attribute__((address_space(1))) unsigned int uint_gas;
typedef __attribute__((address_space(3))) unsigned int uint_las;

__device__ __forceinline__ void gload_lds16(const void* g, void* l) {
  __builtin_amdgcn_global_load_lds((const uint_gas*)g, (uint_las*)l, 16, 0, 0);
}

__device__ __forceinline__ unsigned int f2bf_bits(float f) {
  union { float f; unsigned int u; } v; v.f = f;
  unsigned int r = v.u + 0x7FFFu + ((v.u >> 16) & 1u);
  return r >> 16;
}
__device__ __forceinline__ float bf2f(unsigned int b) {
  union { unsigned int u; float f; } v; v.u = b << 16;
  return v.f;
}
__device__ __forceinline__ unsigned int pack2bf(float a, float b) {
  union { unsigned int u; __bf16 h[2]; } p;
  p.h[0] = (__bf16)a; p.h[1] = (__bf16)b;
  return p.u;
}
__device__ __forceinline__ unsigned short f2h_bits(float f) {
  union { _Float16 h; unsigned short u; } c; c.h = (_Float16)f;
  return c.u;
}
__device__ __forceinline__ float h2f(unsigned short u) {
  union { unsigned short u; _Float16 h; } c; c.u = u;
  return (float)c.h;
}

// ---------------- kernel 0: fp32 -> bf16 conversion (x and weights) ----------------
__global__ __launch_bounds__(256) void convert_kernel(
    const float* __restrict__ x, const float* __restrict__ wq,
    const float* __restrict__ wk, const float* __restrict__ wv,
    unsigned short* __restrict__ xb, unsigned short* __restrict__ Wb)
{
  int i = blockIdx.x * 256 + threadIdx.x;
  const int nx4 = NROWS * DDIM / 4;
  const int nw4 = DDIM * DDIM / 4;
  const float4* src; unsigned short* dst; int j;
  if (i < nx4)              { src = (const float4*)x;  dst = xb;                j = i; }
  else if (i < nx4 +   nw4) { src = (const float4*)wq; dst = Wb;                j = i - nx4; }
  else if (i < nx4 + 2*nw4) { src = (const float4*)wk; dst = Wb + DDIM*DDIM;    j = i - nx4 - nw4; }
  else                      { src = (const float4*)wv; dst = Wb + 2*DDIM*DDIM;  j = i - nx4 - 2*nw4; }
  float4 f = src[j];
  ushort4 o;
  o.x = (unsigned short)f2bf_bits(f.x);
  o.y = (unsigned short)f2bf_bits(f.y);
  o.z = (unsigned short)f2bf_bits(f.z);
  o.w = (unsigned short)f2bf_bits(f.w);
  ((ushort4*)dst)[j] = o;
}

// ---------------- kernel 1: QKV projections + L2 norm + vT ----------------
// grid = 384: out = bid/128 (0=q,1=k,2=v), mb = bid%128 (64-row slab)
__global__ __launch_bounds__(256) void qkv_kernel(
    const float* __restrict__ bq, const float* __restrict__ bk, const float* __restrict__ bv,
    const unsigned short* __restrict__ xb, const unsigned short* __restrict__ Wb,
    unsigned short* __restrict__ qb, unsigned short* __restrict__ kb,
    unsigned short* __restrict__ vb, unsigned short* __restrict__ vT)
{
  __shared__ unsigned short vstage[DDIM * 72];
  const int t = threadIdx.x;
  const int w = t >> 6, l = t & 63;
  const int c = l & 15, g = l >> 4;
  const int out = blockIdx.x / 128;
  const int mb  = blockIdx.x % 128;
  const int row0 = mb * 64;
  const int rw = row0 + w * 16;

  bf16x8 a[8];
  #pragma unroll
  for (int ks = 0; ks < 8; ks++)
    a[ks] = *(const bf16x8*)(xb + (size_t)(rw + c) * DDIM + ks * 32 + g * 8);

  const unsigned short* W = Wb + out * DDIM * DDIM;
  const float* bias = (out == 0) ? bq : (out == 1) ? bk : bv;
  unsigned short* dst = (out == 0) ? qb : (out == 1) ? kb : vb;
  f32x4 vals[16];
  #pragma unroll
  for (int ct = 0; ct < 16; ct++) {
    f32x4 acc = {0.f, 0.f, 0.f, 0.f};
    #pragma unroll
    for (int ks = 0; ks < 8; ks++) {
      bf16x8 b = *(const bf16x8*)(W + (size_t)(ct * 16 + c) * DDIM + ks * 32 + g * 8);
      acc = __builtin_amdgcn_mfma_f32_16x16x32_bf16(a[ks], b, acc, 0, 0, 0);
    }
    float bias_v = bias[ct * 16 + c];
    #pragma unroll
    for (int r = 0; r < 4; r++) acc[r] += bias_v;
    vals[ct] = acc;
  }
  if (out < 2) {   // L2 normalize rows (q, k)
    #pragma unroll
    for (int r = 0; r < 4; r++) {
      float ss = 0.f;
      #pragma unroll
      for (int ct = 0; ct < 16; ct++) ss += vals[ct][r] * vals[ct][r];
      ss += __shfl_xor(ss, 1); ss += __shfl_xor(ss, 2);
      ss += __shfl_xor(ss, 4); ss += __shfl_xor(ss, 8);
      float inv = 1.f / fmaxf(sqrtf(ss), 1e-12f);
      #pragma unroll
      for (int ct = 0; ct < 16; ct++) vals[ct][r] *= inv;
    }
  }
  #pragma unroll
  for (int ct = 0; ct < 16; ct++) {
    #pragma unroll
    for (int r = 0; r < 4; r++) {
      unsigned int bits = f2bf_bits(vals[ct][r]);
      unsigned int ob = (unsigned int)__shfl_xor((int)bits, 1);
      if (!(l & 1))
        *(unsigned int*)(dst + (size_t)(rw + g * 4 + r) * DDIM + ct * 16 + c) =
            bits | (ob << 16);
      if (out == 2)
        vstage[(ct * 16 + c) * 72 + (w * 16 + g * 4 + r)] = (unsigned short)bits;
    }
  }
  if (out == 2) {
    __syncthreads();
    #pragma unroll
    for (int p = 0; p < 8; p++) {
      int dd = (t >> 3) + p * 32;
      int ch = t & 7;
      *(uint4*)(vT + (size_t)dd * NROWS + row0 + ch * 8) =
          *(const uint4*)(vstage + dd * 72 + ch * 8);
    }
  }
}

// ---------------- kernel 2: fused relu-attention, producer-consumer waves ----------------
// 1024 threads = 16 waves @ 4/SIMD. Waves 0-7 (S): hold qa, compute S^T=K.Q^T from
// kbuf, pack P->Pb[cur], stage K, track den. Waves 8-15 (PV): hold oacc, compute
// P(it-1).V(it-1) from Pb[cur^1]/vbuf[cur^1], stage V, write nump. Equal barrier
// counts per path (1 prologue + NT). All K/V/P double-buffered; LDS = 160 KB.
__global__ __launch_bounds__(1024, 4) void attn_kernel(
    const unsigned short* __restrict__ qb, const unsigned short* __restrict__ kb,
    const unsigned short* __restrict__ vT,
    unsigned short* __restrict__ nump, float* __restrict__ denp)
{
  __shared__ __align__(16) char smem[163840];
  char* kbuf = smem;            // [2][32768]
  char* vbuf = smem + 65536;    // [2][32768]
  char* Pb   = smem + 131072;   // [2][16384]

  const int t = threadIdx.x;
  const int w = t >> 6, l = t & 63;
  const int l31 = l & 31, hi = l >> 5;
  const int rw = w & 7;          // role-local wave id
  const int ts = t & 511;        // role-local thread id
  const int bid = blockIdx.x;
  const int split = bid & (KSPLIT - 1);
  const int mb = bid >> 2;
  const int q0 = mb * BM;
  const int kbase0 = split * (NROWS / KSPLIT);
  const char* kbc = (const char*)kb;
  const char* vtc = (const char*)vT;

  if (w < 8) {
    // ===================== PRODUCER: S-waves =====================
    const int sr = rw >> 1, sc = rw & 1;
    const int qrow = sr * 32 + l31;
    const int krl = sc * 32 + l31;
    const int pswz = (qrow & 7) << 4;

    bf16x8 qa[16];
    {
      const unsigned short* qrowp = qb + (size_t)(q0 + qrow) * DDIM + hi * 8;
      #pragma unroll
      for (int m = 0; m < 16; m++) qa[m] = *(const bf16x8*)(qrowp + m * 16);
    }
    float denl = 0.f;

    auto stageK = [&](int buf, int it) {
      const char* ksrc = kbc + (size_t)(kbase0 + it * BK) * 512;
      #pragma unroll
      for (int i = 0; i < 4; i++) {
        int n = i * 512 + ts;
        int row = n >> 5, slot = n & 31;
        // rotation swizzle: lds[row][slot] = K[row][(slot-row)&31]
        gload_lds16(ksrc + row * 512 + (((slot - row) & 31) << 4),
                    kbuf + buf * 32768 + i * 8192 + rw * 1024);
      }
    };

    stageK(0, 0);
    asm volatile("s_waitcnt vmcnt(0)" ::: "memory");
    __builtin_amdgcn_sched_barrier(0);
    __builtin_amdgcn_s_barrier();           // prologue barrier
    __builtin_amdgcn_sched_barrier(0);

    for (int it = 0; it < NT; ++it) {
      const int cur = it & 1;
      if (it + 1 < NT) stageK(cur ^ 1, it + 1);
      __builtin_amdgcn_sched_barrier(0);

      const char* kcur = kbuf + cur * 32768;
      f32x16 sacc = (f32x16){0.f};
      #pragma unroll
      for (int m = 0; m < 16; m++) {
        bf16x8 kf = *(const bf16x8*)(kcur + krl * 512 +
                                     (((m * 2 + hi + krl) & 31) << 4));
        sacc = __builtin_amdgcn_mfma_f32_32x32x16_bf16(kf, qa[m], sacc, 0, 0, 0);
      }
      char* prowP = Pb + cur * 16384 + qrow * 128;
      #pragma unroll
      for (int q = 0; q < 4; q++) {
        float v0 = fmaxf(sacc[4 * q + 0], 0.f);
        float v1 = fmaxf(sacc[4 * q + 1], 0.f);
        float v2 = fmaxf(sacc[4 * q + 2], 0.f);
        float v3 = fmaxf(sacc[4 * q + 3], 0.f);
        denl += (v0 + v1) + (v2 + v3);
        uint2 d2;
        d2.x = pack2bf(v0, v1);
        d2.y = pack2bf(v2, v3);
        *(uint2*)(prowP + ((sc * 64 + q * 16 + hi * 8) ^ pswz)) = d2;
      }
      asm volatile("s_waitcnt vmcnt(0) lgkmcnt(0)" ::: "memory");
      __builtin_amdgcn_sched_barrier(0);
      __builtin_amdgcn_s_barrier();
      __builtin_amdgcn_sched_barrier(0);
    }

    // den: lanes l and l+32 hold the same qrow's two kcol interleaves
    float d = denl;
    d += __shfl_xor(d, 32);
    if (l < 32)
      denp[((size_t)split * 2 + sc) * NROWS + q0 + sr * 32 + l] = d;
  } else {
    // ===================== CONSUMER: PV-waves =====================
    const int pr = rw >> 2, pc = rw & 3;
    const int pr0 = pr * 64 + l31, pr1 = pr * 64 + 32 + l31;

    f32x16 oacc[2][2];
    #pragma unroll
    for (int rt = 0; rt < 2; rt++)
      #pragma unroll
      for (int dt = 0; dt < 2; dt++)
        oacc[rt][dt] = (f32x16){0.f};

    auto stageV = [&](int buf, int it) {
      const char* vsrc = vtc + (size_t)(kbase0 + it * BK) * 2;
      #pragma unroll
      for (int i = 0; i < 4; i++) {
        int n = i * 512 + ts;
        int dd = n >> 3, slot = n & 7;
        // XOR-8 swizzle: lds[d][slot] = vT[d][slot ^ (d&7)]
        gload_lds16(vsrc + (size_t)dd * (NROWS * 2) + ((slot ^ (dd & 7)) * 16),
                    vbuf + buf * 32768 + i * 8192 + rw * 1024);
      }
    };

    __builtin_amdgcn_s_barrier();           // prologue barrier (match producer)
    __builtin_amdgcn_sched_barrier(0);

    for (int it = 0; it < NT; ++it) {
      const int cur = it & 1;
      stageV(cur, it);
      __builtin_amdgcn_sched_barrier(0);

      if (it > 0) {
        const char* Pprev = Pb + (cur ^ 1) * 16384;
        const char* vprev = vbuf + (cur ^ 1) * 32768;
        #pragma unroll
        for (int ch = 0; ch < 4; ch++) {
          const int cb = ch * 32 + hi * 16;
          bf16x8 pa0 = *(const bf16x8*)(Pprev + pr0 * 128 + (cb ^ ((pr0 & 7) << 4)));
          bf16x8 pa1 = *(const bf16x8*)(Pprev + pr1 * 128 + (cb ^ ((pr1 & 7) << 4)));
          #pragma unroll
          for (int dt = 0; dt < 2; dt++) {
            int dl = pc * 64 + dt * 32 + l31;
            bf16x8 vf = *(const bf16x8*)(vprev + dl * 128 + (cb ^ ((dl & 7) << 4)));
            oacc[0][dt] = __builtin_amdgcn_mfma_f32_32x32x16_bf16(pa0, vf, oacc[0][dt], 0, 0, 0);
            oacc[1][dt] = __builtin_amdgcn_mfma_f32_32x32x16_bf16(pa1, vf, oacc[1][dt], 0, 0, 0);
          }
        }
      }
      asm volatile("s_waitcnt vmcnt(0) lgkmcnt(0)" ::: "memory");
      __builtin_amdgcn_sched_barrier(0);
      __builtin_amdgcn_s_barrier();
      __builtin_amdgcn_sched_barrier(0);
    }

    // epilogue: PV(NT-1) — P/V for the last tile are ready after final barrier
    {
      const int last = (NT - 1) & 1;
      const char* Pprev = Pb + last * 16384;
      const char* vprev = vbuf + last * 32768;
      #pragma unroll
      for (int ch = 0; ch < 4; ch++) {
        const int cb = ch * 32 + hi * 16;
        bf16x8 pa0 = *(const bf16x8*)(Pprev + pr0 * 128 + (cb ^ ((pr0 & 7) << 4)));
        bf16x8 pa1 = *(const bf16x8*)(Pprev + pr1 * 128 + (cb ^ ((pr1 & 7) << 4)));
        #pragma unroll
        for (int dt = 0; dt < 2; dt++) {
          int dl = pc * 64 + dt * 32 + l31;
          bf16x8 vf = *(const bf16x8*)(vprev + dl * 128 + (cb ^ ((dl & 7) << 4)));
          oacc[0][dt] = __builtin_amdgcn_mfma_f32_32x32x16_bf16(pa0, vf, oacc[0][dt], 0, 0, 0);
          oacc[1][dt] = __builtin_amdgcn_mfma_f32_32x32x16_bf16(pa1, vf, oacc[1][dt], 0, 0, 0);
        }
      }
    }

    // write numerator partials (fp16). C layout: col=lane&31, row=(r&3)+8*(r>>2)+4*hi
    unsigned short* np = nump + (size_t)split * NROWS * DDIM;
    #pragma unroll
    for (int rt = 0; rt < 2; rt++)
      #pragma unroll
      for (int dt = 0; dt < 2; dt++)
        #pragma unroll
        for (int r = 0; r < 16; r++) {
          int rowg = q0 + pr * 64 + rt * 32 + (r & 3) + 8 * (r >> 2) + 4 * hi;
          int col  = pc * 64 + dt * 32 + l31;
          np[(size_t)rowg * DDIM + col] = f2h_bits(oacc[rt][dt][r]);
        }
  }
}

// ---------------- kernel 3: combine partials, diagonal fix, output ----------------
__global__ __launch_bounds__(256) void combine_kernel(
    const float* __restrict__ x, const unsigned short* __restrict__ qb,
    const unsigned short* __restrict__ kb, const unsigned short* __restrict__ vb,
    const unsigned short* __restrict__ nump, const float* __restrict__ denp,
    float* __restrict__ out)
{
  const int t = threadIdx.x;
  const int w = t >> 6, l = t & 63;
  const int i = blockIdx.x * 4 + w;

  ushort4 q4 = *(const ushort4*)(qb + (size_t)i * DDIM + l * 4);
  ushort4 k4 = *(const ushort4*)(kb + (size_t)i * DDIM + l * 4);
  float s = bf2f(q4.x) * bf2f(k4.x) + bf2f(q4.y) * bf2f(k4.y)
          + bf2f(q4.z) * bf2f(k4.z) + bf2f(q4.w) * bf2f(k4.w);
  #pragma unroll
  for (int m = 1; m < 64; m <<= 1) s += __shfl_xor(s, m);
  float r  = fmaxf(s, 0.f);
  float rb = bf2f(f2bf_bits(r));   // match attn's bf16-rounded P value

  float den = 0.f;
  #pragma unroll
  for (int sp = 0; sp < KSPLIT * 2; sp++)
    den += denp[(size_t)sp * NROWS + i];
  float inv = 1.f / fmaxf(den - rb, 1e-12f);

  const int d0 = l * 4;
  float4 acc = {0.f, 0.f, 0.f, 0.f};
  #pragma unroll
  for (int sp = 0; sp < KSPLIT; sp++) {
    ushort4 u4 = *(const ushort4*)(nump + ((size_t)sp * NROWS + i) * DDIM + d0);
    acc.x += h2f(u4.x); acc.y += h2f(u4.y);
    acc.z += h2f(u4.z); acc.w += h2f(u4.w);
  }
  ushort4 v4 = *(const ushort4*)(vb + (size_t)i * DDIM + d0);
  float4 xx = *(const float4*)(x + (size_t)i * DDIM + d0);
  float4 o;
  o.x = (acc.x - rb * bf2f(v4.x)) * inv + xx.x;
  o.y = (acc.y - rb * bf2f(v4.y)) * inv + xx.y;
  o.z = (acc.z - rb * bf2f(v4.z)) * inv + xx.z;
  o.w = (acc.w - rb * bf2f(v4.w)) * inv + xx.w;
  *(float4*)(out + (size_t)i * DDIM + d0) = o;
}

extern "C" void kernel_launch(void* const* d_in, const int* in_sizes, int n_in,
                              void* d_out, int out_size, void* d_ws, size_t ws_size,
                              hipStream_t stream)
{
  const float* x  = (const float*)d_in[0];
  const float* Wq = (const float*)d_in[1];
  const float* bq = (const float*)d_in[2];
  const float* Wk = (const float*)d_in[3];
  const float* bk = (const float*)d_in[4];
  const float* Wv = (const float*)d_in[5];
  const float* bv = (const float*)d_in[6];

  char* ws = (char*)d_ws;
  unsigned short* xb   = (unsigned short*)(ws + 0);          // 4 MB
  unsigned short* Wb   = (unsigned short*)(ws + 4194304);    // 384 KB
  unsigned short* qb   = (unsigned short*)(ws + 4587520);    // 4 MB
  unsigned short* kb   = (unsigned short*)(ws + 8781824);    // 4 MB
  unsigned short* vb   = (unsigned short*)(ws + 12976128);   // 4 MB
  unsigned short* vT   = (unsigned short*)(ws + 17170432);   // 4 MB
  unsigned short* nump = (unsigned short*)(ws + 21364736);   // 16 MB (4 splits, fp16)
  float* denp = (float*)(ws + 38141952);                     // 256 KB (8 slices)

  convert_kernel<<<2240, 256, 0, stream>>>(x, Wq, Wk, Wv, xb, Wb);
  qkv_kernel<<<384, 256, 0, stream>>>(bq, bk, bv, xb, Wb, qb, kb, vb, vT);
  attn_kernel<<<(NROWS / BM) * KSPLIT, 1024, 0, stream>>>(qb, kb, vT, nump, denp);
  combine_kernel<<<NROWS / 4, 256, 0, stream>>>(x, qb, kb, vb, nump, denp, (float*)d_out);
}

// Round 11
// 123.497 us; speedup vs baseline: 1.4883x; 1.0199x over previous
//
#include <hip/hip_runtime.h>

#define NROWS 8192
#define DDIM  256
#define KSPLIT 4
#define BM 128
#define BK 64
#define NT (NROWS / KSPLIT / BK)   // 32 tiles per split

typedef __bf16 bf16x8 __attribute__((ext_vector_type(8)));
typedef float  f32x4  __attribute__((ext_vector_type(4)));
typedef float  f32x16 __attribute__((ext_vector_type(16)));

typedef __attribute__((address_space(1))) unsigned int uint_gas;
typedef __attribute__((address_space(3))) unsigned int uint_las;

__device__ __forceinline__ void gload_lds16(const void* g, void* l) {
  __builtin_amdgcn_global_load_lds((const uint_gas*)g, (uint_las*)l, 16, 0, 0);
}

__device__ __forceinline__ unsigned int f2bf_bits(float f) {
  union { float f; unsigned int u; } v; v.f = f;
  unsigned int r = v.u + 0x7FFFu + ((v.u >> 16) & 1u);
  return r >> 16;
}
__device__ __forceinline__ float bf2f(unsigned int b) {
  union { unsigned int u; float f; } v; v.u = b << 16;
  return v.f;
}
__device__ __forceinline__ unsigned int pack2bf(float a, float b) {
  union { unsigned int u; __bf16 h[2]; } p;
  p.h[0] = (__bf16)a; p.h[1] = (__bf16)b;
  return p.u;
}
__device__ __forceinline__ unsigned short f2h_bits(float f) {
  union { _Float16 h; unsigned short u; } c; c.h = (_Float16)f;
  return c.u;
}
__device__ __forceinline__ float h2f(unsigned short u) {
  union { unsigned short u; _Float16 h; } c; c.u = u;
  return (float)c.h;
}

// ---------------- kernel 0: fp32 -> bf16, MFMA-fragment-order packing ----------------
// xpack: fid = (rt*8 + ks)*64 + l  -> x[rt*16 + (l&15)][ks*32 + (l>>4)*8 .. +8]
// Wpack: fid = ((out*16+ct)*8 + ks)*64 + l -> W_out[ct*16+(l&15)][ks*32+(l>>4)*8 .. +8]
// Consumers read base + lane*16B: perfectly coalesced 1KB wave loads.
#define NXFRAG (512 * 8 * 64)        // 262144
#define NWFRAG (3 * 16 * 8 * 64)     // 24576
__global__ __launch_bounds__(256) void convert_kernel(
    const float* __restrict__ x, const float* __restrict__ wq,
    const float* __restrict__ wk, const float* __restrict__ wv,
    unsigned short* __restrict__ xp, unsigned short* __restrict__ Wp)
{
  int tid = blockIdx.x * 256 + threadIdx.x;
  const float* src;
  unsigned short* dst;
  int row, col;
  if (tid < NXFRAG) {
    int l = tid & 63, ks = (tid >> 6) & 7, rt = tid >> 9;
    src = x; dst = xp + (size_t)tid * 8;
    row = rt * 16 + (l & 15); col = ks * 32 + (l >> 4) * 8;
  } else {
    int fid = tid - NXFRAG;
    if (fid >= NWFRAG) return;
    int l = fid & 63, ks = (fid >> 6) & 7, ct = (fid >> 9) & 15, out = fid >> 13;
    src = (out == 0) ? wq : (out == 1) ? wk : wv;
    dst = Wp + (size_t)fid * 8;
    row = ct * 16 + (l & 15); col = ks * 32 + (l >> 4) * 8;
  }
  const float* p = src + (size_t)row * DDIM + col;
  float4 f0 = *(const float4*)p;
  float4 f1 = *(const float4*)(p + 4);
  ushort4 o0, o1;
  o0.x = (unsigned short)f2bf_bits(f0.x); o0.y = (unsigned short)f2bf_bits(f0.y);
  o0.z = (unsigned short)f2bf_bits(f0.z); o0.w = (unsigned short)f2bf_bits(f0.w);
  o1.x = (unsigned short)f2bf_bits(f1.x); o1.y = (unsigned short)f2bf_bits(f1.y);
  o1.z = (unsigned short)f2bf_bits(f1.z); o1.w = (unsigned short)f2bf_bits(f1.w);
  *(ushort4*)dst = o0;
  *(ushort4*)(dst + 4) = o1;
}

// ---------------- kernel 1: QKV projections + L2 norm + vT ----------------
// grid = 384: out = bid/128 (0=q,1=k,2=v), mb = bid%128 (64-row slab)
// All MFMA operands load coalesced from fragment-packed xp/Wp (L2-resident).
__global__ __launch_bounds__(256) void qkv_kernel(
    const float* __restrict__ bq, const float* __restrict__ bk, const float* __restrict__ bv,
    const unsigned short* __restrict__ xp, const unsigned short* __restrict__ Wp,
    unsigned short* __restrict__ qb, unsigned short* __restrict__ kb,
    unsigned short* __restrict__ vb, unsigned short* __restrict__ vT)
{
  __shared__ unsigned short vstage[DDIM * 72];
  const int t = threadIdx.x;
  const int w = t >> 6, l = t & 63;
  const int c = l & 15, g = l >> 4;
  const int out = blockIdx.x / 128;
  const int mb  = blockIdx.x % 128;
  const int row0 = mb * 64;
  const int rw = row0 + w * 16;
  const int rt = mb * 4 + w;           // global 16-row tile id

  bf16x8 a[8];
  #pragma unroll
  for (int ks = 0; ks < 8; ks++)
    a[ks] = *(const bf16x8*)(xp + ((size_t)(rt * 8 + ks) * 64 + l) * 8);

  const float* bias = (out == 0) ? bq : (out == 1) ? bk : bv;
  unsigned short* dst = (out == 0) ? qb : (out == 1) ? kb : vb;
  f32x4 vals[16];
  #pragma unroll
  for (int ct = 0; ct < 16; ct++) {
    f32x4 acc = {0.f, 0.f, 0.f, 0.f};
    #pragma unroll
    for (int ks = 0; ks < 8; ks++) {
      bf16x8 b = *(const bf16x8*)(Wp + ((size_t)((out * 16 + ct) * 8 + ks) * 64 + l) * 8);
      acc = __builtin_amdgcn_mfma_f32_16x16x32_bf16(a[ks], b, acc, 0, 0, 0);
    }
    float bias_v = bias[ct * 16 + c];
    #pragma unroll
    for (int r = 0; r < 4; r++) acc[r] += bias_v;
    vals[ct] = acc;
  }
  if (out < 2) {   // L2 normalize rows (q, k)
    #pragma unroll
    for (int r = 0; r < 4; r++) {
      float ss = 0.f;
      #pragma unroll
      for (int ct = 0; ct < 16; ct++) ss += vals[ct][r] * vals[ct][r];
      ss += __shfl_xor(ss, 1); ss += __shfl_xor(ss, 2);
      ss += __shfl_xor(ss, 4); ss += __shfl_xor(ss, 8);
      float inv = 1.f / fmaxf(sqrtf(ss), 1e-12f);
      #pragma unroll
      for (int ct = 0; ct < 16; ct++) vals[ct][r] *= inv;
    }
  }
  #pragma unroll
  for (int ct = 0; ct < 16; ct++) {
    #pragma unroll
    for (int r = 0; r < 4; r++) {
      unsigned int bits = f2bf_bits(vals[ct][r]);
      unsigned int ob = (unsigned int)__shfl_xor((int)bits, 1);
      if (!(l & 1))
        *(unsigned int*)(dst + (size_t)(rw + g * 4 + r) * DDIM + ct * 16 + c) =
            bits | (ob << 16);
      if (out == 2)
        vstage[(ct * 16 + c) * 72 + (w * 16 + g * 4 + r)] = (unsigned short)bits;
    }
  }
  if (out == 2) {
    __syncthreads();
    #pragma unroll
    for (int p = 0; p < 8; p++) {
      int dd = (t >> 3) + p * 32;
      int ch = t & 7;
      *(uint4*)(vT + (size_t)dd * NROWS + row0 + ch * 8) =
          *(const uint4*)(vstage + dd * 72 + ch * 8);
    }
  }
}

// ---------------- kernel 2: fused relu-attention, producer-consumer waves ----------------
// 1024 threads = 16 waves @ 4/SIMD. Waves 0-7 (S): hold qa, compute S^T=K.Q^T from
// kbuf, pack P->Pb[cur], stage K, track den. Waves 8-15 (PV): hold oacc, compute
// P(it-1).V(it-1) from Pb[cur^1]/vbuf[cur^1], stage V, write nump. Equal barrier
// counts per path (1 prologue + NT). All K/V/P double-buffered; LDS = 160 KB.
__global__ __launch_bounds__(1024, 4) void attn_kernel(
    const unsigned short* __restrict__ qb, const unsigned short* __restrict__ kb,
    const unsigned short* __restrict__ vT,
    unsigned short* __restrict__ nump, float* __restrict__ denp)
{
  __shared__ __align__(16) char smem[163840];
  char* kbuf = smem;            // [2][32768]
  char* vbuf = smem + 65536;    // [2][32768]
  char* Pb   = smem + 131072;   // [2][16384]

  const int t = threadIdx.x;
  const int w = t >> 6, l = t & 63;
  const int l31 = l & 31, hi = l >> 5;
  const int rw = w & 7;          // role-local wave id
  const int ts = t & 511;        // role-local thread id
  const int bid = blockIdx.x;
  const int split = bid & (KSPLIT - 1);
  const int mb = bid >> 2;
  const int q0 = mb * BM;
  const int kbase0 = split * (NROWS / KSPLIT);
  const char* kbc = (const char*)kb;
  const char* vtc = (const char*)vT;

  if (w < 8) {
    // ===================== PRODUCER: S-waves =====================
    const int sr = rw >> 1, sc = rw & 1;
    const int qrow = sr * 32 + l31;
    const int krl = sc * 32 + l31;
    const int pswz = (qrow & 7) << 4;

    bf16x8 qa[16];
    {
      const unsigned short* qrowp = qb + (size_t)(q0 + qrow) * DDIM + hi * 8;
      #pragma unroll
      for (int m = 0; m < 16; m++) qa[m] = *(const bf16x8*)(qrowp + m * 16);
    }
    float denl = 0.f;

    auto stageK = [&](int buf, int it) {
      const char* ksrc = kbc + (size_t)(kbase0 + it * BK) * 512;
      #pragma unroll
      for (int i = 0; i < 4; i++) {
        int n = i * 512 + ts;
        int row = n >> 5, slot = n & 31;
        // rotation swizzle: lds[row][slot] = K[row][(slot-row)&31]
        gload_lds16(ksrc + row * 512 + (((slot - row) & 31) << 4),
                    kbuf + buf * 32768 + i * 8192 + rw * 1024);
      }
    };

    stageK(0, 0);
    asm volatile("s_waitcnt vmcnt(0)" ::: "memory");
    __builtin_amdgcn_sched_barrier(0);
    __builtin_amdgcn_s_barrier();           // prologue barrier
    __builtin_amdgcn_sched_barrier(0);

    for (int it = 0; it < NT; ++it) {
      const int cur = it & 1;
      if (it + 1 < NT) stageK(cur ^ 1, it + 1);
      __builtin_amdgcn_sched_barrier(0);

      const char* kcur = kbuf + cur * 32768;
      f32x16 sacc = (f32x16){0.f};
      #pragma unroll
      for (int m = 0; m < 16; m++) {
        bf16x8 kf = *(const bf16x8*)(kcur + krl * 512 +
                                     (((m * 2 + hi + krl) & 31) << 4));
        sacc = __builtin_amdgcn_mfma_f32_32x32x16_bf16(kf, qa[m], sacc, 0, 0, 0);
      }
      char* prowP = Pb + cur * 16384 + qrow * 128;
      #pragma unroll
      for (int q = 0; q < 4; q++) {
        float v0 = fmaxf(sacc[4 * q + 0], 0.f);
        float v1 = fmaxf(sacc[4 * q + 1], 0.f);
        float v2 = fmaxf(sacc[4 * q + 2], 0.f);
        float v3 = fmaxf(sacc[4 * q + 3], 0.f);
        denl += (v0 + v1) + (v2 + v3);
        uint2 d2;
        d2.x = pack2bf(v0, v1);
        d2.y = pack2bf(v2, v3);
        *(uint2*)(prowP + ((sc * 64 + q * 16 + hi * 8) ^ pswz)) = d2;
      }
      asm volatile("s_waitcnt vmcnt(0) lgkmcnt(0)" ::: "memory");
      __builtin_amdgcn_sched_barrier(0);
      __builtin_amdgcn_s_barrier();
      __builtin_amdgcn_sched_barrier(0);
    }

    // den: lanes l and l+32 hold the same qrow's two kcol interleaves
    float d = denl;
    d += __shfl_xor(d, 32);
    if (l < 32)
      denp[((size_t)split * 2 + sc) * NROWS + q0 + sr * 32 + l] = d;
  } else {
    // ===================== CONSUMER: PV-waves =====================
    const int pr = rw >> 2, pc = rw & 3;
    const int pr0 = pr * 64 + l31, pr1 = pr * 64 + 32 + l31;

    f32x16 oacc[2][2];
    #pragma unroll
    for (int rt = 0; rt < 2; rt++)
      #pragma unroll
      for (int dt = 0; dt < 2; dt++)
        oacc[rt][dt] = (f32x16){0.f};

    auto stageV = [&](int buf, int it) {
      const char* vsrc = vtc + (size_t)(kbase0 + it * BK) * 2;
      #pragma unroll
      for (int i = 0; i < 4; i++) {
        int n = i * 512 + ts;
        int dd = n >> 3, slot = n & 7;
        // XOR-8 swizzle: lds[d][slot] = vT[d][slot ^ (d&7)]
        gload_lds16(vsrc + (size_t)dd * (NROWS * 2) + ((slot ^ (dd & 7)) * 16),
                    vbuf + buf * 32768 + i * 8192 + rw * 1024);
      }
    };

    __builtin_amdgcn_s_barrier();           // prologue barrier (match producer)
    __builtin_amdgcn_sched_barrier(0);

    for (int it = 0; it < NT; ++it) {
      const int cur = it & 1;
      stageV(cur, it);
      __builtin_amdgcn_sched_barrier(0);

      if (it > 0) {
        const char* Pprev = Pb + (cur ^ 1) * 16384;
        const char* vprev = vbuf + (cur ^ 1) * 32768;
        #pragma unroll
        for (int ch = 0; ch < 4; ch++) {
          const int cb = ch * 32 + hi * 16;
          bf16x8 pa0 = *(const bf16x8*)(Pprev + pr0 * 128 + (cb ^ ((pr0 & 7) << 4)));
          bf16x8 pa1 = *(const bf16x8*)(Pprev + pr1 * 128 + (cb ^ ((pr1 & 7) << 4)));
          #pragma unroll
          for (int dt = 0; dt < 2; dt++) {
            int dl = pc * 64 + dt * 32 + l31;
            bf16x8 vf = *(const bf16x8*)(vprev + dl * 128 + (cb ^ ((dl & 7) << 4)));
            oacc[0][dt] = __builtin_amdgcn_mfma_f32_32x32x16_bf16(pa0, vf, oacc[0][dt], 0, 0, 0);
            oacc[1][dt] = __builtin_amdgcn_mfma_f32_32x32x16_bf16(pa1, vf, oacc[1][dt], 0, 0, 0);
          }
        }
      }
      asm volatile("s_waitcnt vmcnt(0) lgkmcnt(0)" ::: "memory");
      __builtin_amdgcn_sched_barrier(0);
      __builtin_amdgcn_s_barrier();
      __builtin_amdgcn_sched_barrier(0);
    }

    // epilogue: PV(NT-1) — P/V for the last tile are ready after final barrier
    {
      const int last = (NT - 1) & 1;
      const char* Pprev = Pb + last * 16384;
      const char* vprev = vbuf + last * 32768;
      #pragma unroll
      for (int ch = 0; ch < 4; ch++) {
        const int cb = ch * 32 + hi * 16;
        bf16x8 pa0 = *(const bf16x8*)(Pprev + pr0 * 128 + (cb ^ ((pr0 & 7) << 4)));
        bf16x8 pa1 = *(const bf16x8*)(Pprev + pr1 * 128 + (cb ^ ((pr1 & 7) << 4)));
        #pragma unroll
        for (int dt = 0; dt < 2; dt++) {
          int dl = pc * 64 + dt * 32 + l31;
          bf16x8 vf = *(const bf16x8*)(vprev + dl * 128 + (cb ^ ((dl & 7) << 4)));
          oacc[0][dt] = __builtin_amdgcn_mfma_f32_32x32x16_bf16(pa0, vf, oacc[0][dt], 0, 0, 0);
          oacc[1][dt] = __builtin_amdgcn_mfma_f32_32x32x16_bf16(pa1, vf, oacc[1][dt], 0, 0, 0);
        }
      }
    }

    // write numerator partials (fp16). C layout: col=lane&31, row=(r&3)+8*(r>>2)+4*hi
    unsigned short* np = nump + (size_t)split * NROWS * DDIM;
    #pragma unroll
    for (int rt = 0; rt < 2; rt++)
      #pragma unroll
      for (int dt = 0; dt < 2; dt++)
        #pragma unroll
        for (int r = 0; r < 16; r++) {
          int rowg = q0 + pr * 64 + rt * 32 + (r & 3) + 8 * (r >> 2) + 4 * hi;
          int col  = pc * 64 + dt * 32 + l31;
          np[(size_t)rowg * DDIM + col] = f2h_bits(oacc[rt][dt][r]);
        }
  }
}

// ---------------- kernel 3: combine partials, diagonal fix, output ----------------
__global__ __launch_bounds__(256) void combine_kernel(
    const float* __restrict__ x, const unsigned short* __restrict__ qb,
    const unsigned short* __restrict__ kb, const unsigned short* __restrict__ vb,
    const unsigned short* __restrict__ nump, const float* __restrict__ denp,
    float* __restrict__ out)
{
  const int t = threadIdx.x;
  const int w = t >> 6, l = t & 63;
  const int i = blockIdx.x * 4 + w;

  ushort4 q4 = *(const ushort4*)(qb + (size_t)i * DDIM + l * 4);
  ushort4 k4 = *(const ushort4*)(kb + (size_t)i * DDIM + l * 4);
  float s = bf2f(q4.x) * bf2f(k4.x) + bf2f(q4.y) * bf2f(k4.y)
          + bf2f(q4.z) * bf2f(k4.z) + bf2f(q4.w) * bf2f(k4.w);
  #pragma unroll
  for (int m = 1; m < 64; m <<= 1) s += __shfl_xor(s, m);
  float r  = fmaxf(s, 0.f);
  float rb = bf2f(f2bf_bits(r));   // match attn's bf16-rounded P value

  float den = 0.f;
  #pragma unroll
  for (int sp = 0; sp < KSPLIT * 2; sp++)
    den += denp[(size_t)sp * NROWS + i];
  float inv = 1.f / fmaxf(den - rb, 1e-12f);

  const int d0 = l * 4;
  float4 acc = {0.f, 0.f, 0.f, 0.f};
  #pragma unroll
  for (int sp = 0; sp < KSPLIT; sp++) {
    ushort4 u4 = *(const ushort4*)(nump + ((size_t)sp * NROWS + i) * DDIM + d0);
    acc.x += h2f(u4.x); acc.y += h2f(u4.y);
    acc.z += h2f(u4.z); acc.w += h2f(u4.w);
  }
  ushort4 v4 = *(const ushort4*)(vb + (size_t)i * DDIM + d0);
  float4 xx = *(const float4*)(x + (size_t)i * DDIM + d0);
  float4 o;
  o.x = (acc.x - rb * bf2f(v4.x)) * inv + xx.x;
  o.y = (acc.y - rb * bf2f(v4.y)) * inv + xx.y;
  o.z = (acc.z - rb * bf2f(v4.z)) * inv + xx.z;
  o.w = (acc.w - rb * bf2f(v4.w)) * inv + xx.w;
  *(float4*)(out + (size_t)i * DDIM + d0) = o;
}

extern "C" void kernel_launch(void* const* d_in, const int* in_sizes, int n_in,
                              void* d_out, int out_size, void* d_ws, size_t ws_size,
                              hipStream_t stream)
{
  const float* x  = (const float*)d_in[0];
  const float* Wq = (const float*)d_in[1];
  const float* bq = (const float*)d_in[2];
  const float* Wk = (const float*)d_in[3];
  const float* bk = (const float*)d_in[4];
  const float* Wv = (const float*)d_in[5];
  const float* bv = (const float*)d_in[6];

  char* ws = (char*)d_ws;
  unsigned short* xp   = (unsigned short*)(ws + 0);          // 4 MB (fragment-packed x)
  unsigned short* Wp   = (unsigned short*)(ws + 4194304);    // 384 KB (fragment-packed W)
  unsigned short* qb   = (unsigned short*)(ws + 4587520);    // 4 MB
  unsigned short* kb   = (unsigned short*)(ws + 8781824);    // 4 MB
  unsigned short* vb   = (unsigned short*)(ws + 12976128);   // 4 MB
  unsigned short* vT   = (unsigned short*)(ws + 17170432);   // 4 MB
  unsigned short* nump = (unsigned short*)(ws + 21364736);   // 16 MB (4 splits, fp16)
  float* denp = (float*)(ws + 38141952);                     // 256 KB (8 slices)

  convert_kernel<<<1120, 256, 0, stream>>>(x, Wq, Wk, Wv, xp, Wp);
  qkv_kernel<<<384, 256, 0, stream>>>(bq, bk, bv, xp, Wp, qb, kb, vb, vT);
  attn_kernel<<<(NROWS / BM) * KSPLIT, 1024, 0, stream>>>(qb, kb, vT, nump, denp);
  combine_kernel<<<NROWS / 4, 256, 0, stream>>>(x, qb, kb, vb, nump, denp, (float*)d_out);
}